// Round 1
// baseline (699.616 us; speedup 1.0000x reference)
//
#include <hip/hip_runtime.h>
#include <math.h>

#define NN 512
#define NBC 128   // B*2

// ---------------- degree: dinv[bc][i] = rsqrt(1 + sum_j adj[bc][i][j]) -----
__global__ __launch_bounds__(256) void k_rowsum(const float* __restrict__ adj,
                                                float* __restrict__ dinv) {
    int wave = blockIdx.x * 4 + (threadIdx.x >> 6);
    int lane = threadIdx.x & 63;
    const float4* row = (const float4*)(adj + (size_t)wave * NN);
    float4 v0 = row[lane], v1 = row[lane + 64];
    float s = v0.x + v0.y + v0.z + v0.w + v1.x + v1.y + v1.z + v1.w;
    #pragma unroll
    for (int off = 32; off; off >>= 1) s += __shfl_down(s, off, 64);
    if (lane == 0) dinv[wave] = rsqrtf(1.0f + s);
}

// ---------------- big GEMM: X[i,h] = act(d_i*((adj@Zc)[i,h] + Zc[i,h]) + b[h])
// SHARED: layer1, Zc on the fly = d_j * W1[j,h] (W shared across bc)
template<int H, int HP, bool SHARED, bool ACT>
__global__ __launch_bounds__(256) void k_biggemm(
    const float* __restrict__ adj, const float* __restrict__ zcg,
    const float* __restrict__ wp, const float* __restrict__ wn,
    const float* __restrict__ bp, const float* __restrict__ bn,
    const float* __restrict__ dinv, float* __restrict__ xout)
{
    constexpr int CPT = HP / 16;   // cols per thread
    constexpr int KT = 64;
    __shared__ float a_s[64 * 68];       // adj tile [row][k], pad 68 for bank-free f4
    __shared__ float z_s[KT * H];        // Zc tile [k][h]
    const int bc = blockIdx.y;
    const int rt = blockIdx.x;
    const int t  = threadIdx.x;
    const int tx = t & 15, ty = t >> 4;
    const float* A    = adj + (size_t)bc * NN * NN + (size_t)rt * 64 * NN;
    const float* dloc = dinv + bc * NN;
    const float* ZG   = SHARED ? ((bc & 1) ? wn : wp) : (zcg + (size_t)bc * NN * H);
    const float* bias = (bc & 1) ? bn : bp;

    float acc[4][CPT];
    #pragma unroll
    for (int r = 0; r < 4; ++r)
        #pragma unroll
        for (int u = 0; u < CPT; ++u) acc[r][u] = 0.f;

    for (int kb = 0; kb < NN; kb += KT) {
        __syncthreads();
        // stage adj tile 64x64 (float4 coalesced)
        #pragma unroll
        for (int l = 0; l < 4; ++l) {
            int idx = t + l * 256;
            int r = idx >> 4, q = idx & 15;
            float4 v = *(const float4*)(A + (size_t)r * NN + kb + q * 4);
            *(float4*)(a_s + r * 68 + q * 4) = v;
        }
        // stage Zc tile KTxH
        constexpr int NZ4 = KT * H / 4;
        for (int idx = t; idx < NZ4; idx += 256) {
            int k = idx / (H / 4), hq = idx % (H / 4);
            float4 v = *(const float4*)(ZG + (size_t)(kb + k) * H + hq * 4);
            if (SHARED) {
                float dk = dloc[kb + k];
                v.x *= dk; v.y *= dk; v.z *= dk; v.w *= dk;
            }
            *(float4*)(z_s + k * H + hq * 4) = v;
        }
        __syncthreads();
        #pragma unroll 8
        for (int k = 0; k < KT; ++k) {
            float ar[4];
            #pragma unroll
            for (int r = 0; r < 4; ++r) ar[r] = a_s[(ty * 4 + r) * 68 + k];
            float zv[CPT];
            #pragma unroll
            for (int u = 0; u < CPT; ++u) {
                int h = tx * CPT + u;
                if (H < HP && h >= H) h = 0;   // layer4 pad guard (compile-time)
                zv[u] = z_s[k * H + h];
            }
            #pragma unroll
            for (int r = 0; r < 4; ++r)
                #pragma unroll
                for (int u = 0; u < CPT; ++u)
                    acc[r][u] += ar[r] * zv[u];
        }
    }
    #pragma unroll
    for (int r = 0; r < 4; ++r) {
        int i = rt * 64 + ty * 4 + r;
        float di = dloc[i];
        #pragma unroll
        for (int u = 0; u < CPT; ++u) {
            int h = tx * CPT + u;
            if (H < HP && h >= H) continue;
            float self = SHARED ? di * ZG[(size_t)i * H + h] : ZG[(size_t)i * H + h];
            float v = di * (acc[r][u] + self) + bias[h];
            if (ACT) v = v >= 0.f ? v : 0.2f * v;
            xout[((size_t)bc * NN + i) * H + h] = v;
        }
    }
}

// ---------------- small GEMM: Zc[j,h] = d_j * sum_p X[j,p]*W[p,h] ----------
template<int HI, int HO>
__global__ __launch_bounds__(256) void k_smallgemm(
    const float* __restrict__ xin, const float* __restrict__ wp,
    const float* __restrict__ wn, const float* __restrict__ dinv,
    float* __restrict__ zc)
{
    constexpr int CPT = (HO >= 16) ? HO / 16 : 1;
    constexpr int XS = HI + 4;
    __shared__ float x_s[32 * XS];
    __shared__ float w_s[HI * HO];
    const int bc = blockIdx.y, jt = blockIdx.x, t = threadIdx.x;
    const int tx = t & 15, ty = t >> 4;
    const float* W = (bc & 1) ? wn : wp;
    const float* X = xin + ((size_t)bc * NN + jt * 32) * HI;
    for (int idx = t; idx < HI * HO / 4; idx += 256)
        *(float4*)(w_s + idx * 4) = *(const float4*)(W + idx * 4);
    for (int idx = t; idx < 32 * HI / 4; idx += 256) {
        int r = idx / (HI / 4), q = idx % (HI / 4);
        *(float4*)(x_s + r * XS + q * 4) = *(const float4*)(X + (size_t)r * HI + q * 4);
    }
    __syncthreads();
    float acc[2][CPT];
    #pragma unroll
    for (int r = 0; r < 2; ++r)
        #pragma unroll
        for (int u = 0; u < CPT; ++u) acc[r][u] = 0.f;
    #pragma unroll 4
    for (int p = 0; p < HI; ++p) {
        float xr[2];
        #pragma unroll
        for (int r = 0; r < 2; ++r) xr[r] = x_s[(ty * 2 + r) * XS + p];
        float wv[CPT];
        #pragma unroll
        for (int u = 0; u < CPT; ++u) {
            int h = tx * CPT + u;
            if (HO < 16 && h >= HO) h = 0;
            wv[u] = w_s[p * HO + h];
        }
        #pragma unroll
        for (int r = 0; r < 2; ++r)
            #pragma unroll
            for (int u = 0; u < CPT; ++u) acc[r][u] += xr[r] * wv[u];
    }
    const float* dloc = dinv + bc * NN;
    #pragma unroll
    for (int r = 0; r < 2; ++r) {
        int j = jt * 32 + ty * 2 + r;
        float dj = dloc[j];
        #pragma unroll
        for (int u = 0; u < CPT; ++u) {
            int h = tx * CPT + u;
            if (HO < 16 && h >= HO) continue;
            zc[((size_t)bc * NN + j) * HO + h] = dj * acc[r][u];
        }
    }
}

// ---------------- DCL head: L[bc][o*512+n] = sum_i w[o,i]*conv4flat[i*512+n]+bv[o]
__global__ __launch_bounds__(256) void k_dcl(
    const float* __restrict__ x3, const float* __restrict__ x4,
    const float* __restrict__ wc, const int* __restrict__ task,
    float* __restrict__ L)
{
    __shared__ float ps[8][32];
    __shared__ float xf[32];
    __shared__ float pr[72];
    const int bc = blockIdx.x, t = threadIdx.x;
    const float* X3 = x3 + (size_t)bc * NN * 32;
    {
        int col = t & 31, rg = t >> 5;
        float s = 0.f;
        for (int r = rg; r < NN; r += 8) s += X3[r * 32 + col];
        ps[rg][col] = s;
    }
    __syncthreads();
    if (t < 32) {
        float s = 0.f;
        #pragma unroll
        for (int g = 0; g < 8; ++g) s += ps[g][t];
        xf[t] = s * (1.0f / 512.0f);   // mean over N
    }
    __syncthreads();
    if (t < 72) {
        int tid = task[bc >> 1];
        const float* wr = wc + t * 48;
        float s = wr[32 + tid];        // one-hot picks column 32+task_id
        #pragma unroll
        for (int j = 0; j < 32; ++j) s += wr[j] * xf[j];
        pr[t] = s;
    }
    __syncthreads();
    const float* X4 = x4 + (size_t)bc * 4096;   // conv4 flat (head reshape)
    float* Lb = L + (size_t)bc * 4096;
    #pragma unroll
    for (int rep = 0; rep < 2; ++rep) {
        int n = rep * 256 + t;
        float hi[8];
        #pragma unroll
        for (int i = 0; i < 8; ++i) hi[i] = X4[i * 512 + n];
        #pragma unroll
        for (int o = 0; o < 8; ++o) {
            float s = pr[64 + o];
            #pragma unroll
            for (int i = 0; i < 8; ++i) s += pr[o * 8 + i] * hi[i];
            Lb[o * 512 + n] = s;
        }
    }
}

// ---------------- final: out[bc][n][m] = softplus(-cc_n . cc_m) ------------
__global__ __launch_bounds__(256) void k_final(const float* __restrict__ L,
                                               float* __restrict__ out)
{
    __shared__ float sc[4096];   // cc for this (b,c): [n][8]
    const int bcid = blockIdx.y;
    const int b = bcid >> 1, c = bcid & 1;
    const int nt = blockIdx.x, t = threadIdx.x;
    const float* Lp = L + (size_t)(b * 2) * 4096;
    const float* Ln = Lp + 4096;
    // cc[b][c][n2][o] = concat(lp,ln) flat reinterpretation
    for (int rep = 0; rep < 16; ++rep) {
        int e = rep * 256 + t;
        int f = c * 4096 + e;
        int n = f >> 4, k = f & 15;
        sc[e] = (k < 8) ? Lp[n * 8 + k] : Ln[n * 8 + k - 8];
    }
    __syncthreads();
    const int tx = t & 63, ty = t >> 6;
    const int n0 = nt * 32 + ty * 8;
    float cn[8][8];
    #pragma unroll
    for (int i = 0; i < 8; ++i)
        #pragma unroll
        for (int o = 0; o < 8; ++o) cn[i][o] = sc[(n0 + i) * 8 + o];
    float* ob = out + (size_t)bcid * NN * NN;
    #pragma unroll 2
    for (int mg = 0; mg < 8; ++mg) {
        int m = tx + mg * 64;
        float cm[8];
        #pragma unroll
        for (int o = 0; o < 8; ++o) cm[o] = sc[m * 8 + o];
        #pragma unroll
        for (int i = 0; i < 8; ++i) {
            float s = 0.f;
            #pragma unroll
            for (int o = 0; o < 8; ++o) s += cn[i][o] * cm[o];
            // softplus(-s), numerically stable
            float r = (s >= 0.f) ? log1pf(__expf(-s)) : (log1pf(__expf(s)) - s);
            ob[(size_t)(n0 + i) * NN + m] = r;
        }
    }
}

extern "C" void kernel_launch(void* const* d_in, const int* in_sizes, int n_in,
                              void* d_out, int out_size, void* d_ws, size_t ws_size,
                              hipStream_t stream)
{
    const float* adj = (const float*)d_in[0];
    const int*  task = (const int*)d_in[1];
    const float* w1p = (const float*)d_in[2];  const float* b1p = (const float*)d_in[3];
    const float* w2p = (const float*)d_in[4];  const float* b2p = (const float*)d_in[5];
    const float* w3p = (const float*)d_in[6];  const float* b3p = (const float*)d_in[7];
    const float* w4p = (const float*)d_in[8];  const float* b4p = (const float*)d_in[9];
    const float* w1n = (const float*)d_in[10]; const float* b1n = (const float*)d_in[11];
    const float* w2n = (const float*)d_in[12]; const float* b2n = (const float*)d_in[13];
    const float* w3n = (const float*)d_in[14]; const float* b3n = (const float*)d_in[15];
    const float* w4n = (const float*)d_in[16]; const float* b4n = (const float*)d_in[17];
    const float* wc  = (const float*)d_in[18];

    float* ws   = (float*)d_ws;
    float* dinv = ws;                 // 65,536 floats
    float* XA   = ws + 65536;         // 8,388,608  (X1 then reused for X2)
    float* X3   = XA + 8388608;       // 2,097,152  (conv3, kept for DCL)
    float* X4   = X3 + 2097152;       //   524,288  (conv4)
    float* L    = X4 + 524288;        //   524,288  (logits flat, (8,512) layout)
    float* ZC   = L  + 524288;        // 4,194,304  (Zc scratch, reused per layer)
    (void)in_sizes; (void)n_in; (void)out_size; (void)ws_size;

    k_rowsum<<<dim3(NBC * NN / 4), dim3(256), 0, stream>>>(adj, dinv);
    // layer 1: H=128, Zc folded from shared W1 (Zc = d_j * W1[j,h])
    k_biggemm<128,128,true ,true ><<<dim3(8,128), 256, 0, stream>>>(adj, nullptr, w1p, w1n, b1p, b1n, dinv, XA);
    k_smallgemm<128,64><<<dim3(16,128), 256, 0, stream>>>(XA, w2p, w2n, dinv, ZC);
    k_biggemm<64,64,false,true ><<<dim3(8,128), 256, 0, stream>>>(adj, ZC, nullptr, nullptr, b2p, b2n, dinv, XA);
    k_smallgemm<64,32><<<dim3(16,128), 256, 0, stream>>>(XA, w3p, w3n, dinv, ZC);
    k_biggemm<32,32,false,true ><<<dim3(8,128), 256, 0, stream>>>(adj, ZC, nullptr, nullptr, b3p, b3n, dinv, X3);
    k_smallgemm<32,8><<<dim3(16,128), 256, 0, stream>>>(X3, w4p, w4n, dinv, ZC);
    k_biggemm<8,16,false,false><<<dim3(8,128), 256, 0, stream>>>(adj, ZC, nullptr, nullptr, b4p, b4n, dinv, X4);
    k_dcl<<<dim3(128), 256, 0, stream>>>(X3, X4, wc, task, L);
    k_final<<<dim3(16,128), 256, 0, stream>>>(L, (float*)d_out);
}

// Round 2
// 617.035 us; speedup vs baseline: 1.1338x; 1.1338x over previous
//
#include <hip/hip_runtime.h>
#include <math.h>

#define NN 512
#define NBC 128   // B*2

// ---------------- degree: dinv[bc][i] = rsqrt(1 + sum_j adj[bc][i][j]) -----
__global__ __launch_bounds__(256) void k_rowsum(const float* __restrict__ adj,
                                                float* __restrict__ dinv) {
    int wave = blockIdx.x * 4 + (threadIdx.x >> 6);
    int lane = threadIdx.x & 63;
    const float4* row = (const float4*)(adj + (size_t)wave * NN);
    float4 v0 = row[lane], v1 = row[lane + 64];
    float s = v0.x + v0.y + v0.z + v0.w + v1.x + v1.y + v1.z + v1.w;
    #pragma unroll
    for (int off = 32; off; off >>= 1) s += __shfl_down(s, off, 64);
    if (lane == 0) dinv[wave] = rsqrtf(1.0f + s);
}

// ---------------- big GEMM: X[i,h] = act(d_i*((adj@Zc)[i,h] + Zc[i,h]) + b[h])
// SHARED: layer1, Zc on the fly = d_j * W1[j,h] (W shared across bc)
template<int H, int HP, bool SHARED, bool ACT>
__global__ __launch_bounds__(256) void k_biggemm(
    const float* __restrict__ adj, const float* __restrict__ zcg,
    const float* __restrict__ wp, const float* __restrict__ wn,
    const float* __restrict__ bp, const float* __restrict__ bn,
    const float* __restrict__ dinv, float* __restrict__ xout)
{
    constexpr int CPT = HP / 16;   // cols per thread
    constexpr int KT = 64;
    __shared__ float a_s[64 * 68];       // adj tile [row][k], pad 68 for bank-free f4
    __shared__ float z_s[KT * H];        // Zc tile [k][h]
    const int bc = blockIdx.y;
    const int rt = blockIdx.x;
    const int t  = threadIdx.x;
    const int tx = t & 15, ty = t >> 4;
    const float* A    = adj + (size_t)bc * NN * NN + (size_t)rt * 64 * NN;
    const float* dloc = dinv + bc * NN;
    const float* ZG   = SHARED ? ((bc & 1) ? wn : wp) : (zcg + (size_t)bc * NN * H);
    const float* bias = (bc & 1) ? bn : bp;

    float acc[4][CPT];
    #pragma unroll
    for (int r = 0; r < 4; ++r)
        #pragma unroll
        for (int u = 0; u < CPT; ++u) acc[r][u] = 0.f;

    for (int kb = 0; kb < NN; kb += KT) {
        __syncthreads();
        // stage adj tile 64x64 (float4 coalesced)
        #pragma unroll
        for (int l = 0; l < 4; ++l) {
            int idx = t + l * 256;
            int r = idx >> 4, q = idx & 15;
            float4 v = *(const float4*)(A + (size_t)r * NN + kb + q * 4);
            *(float4*)(a_s + r * 68 + q * 4) = v;
        }
        // stage Zc tile KTxH
        constexpr int NZ4 = KT * H / 4;
        for (int idx = t; idx < NZ4; idx += 256) {
            int k = idx / (H / 4), hq = idx % (H / 4);
            float4 v = *(const float4*)(ZG + (size_t)(kb + k) * H + hq * 4);
            if (SHARED) {
                float dk = dloc[kb + k];
                v.x *= dk; v.y *= dk; v.z *= dk; v.w *= dk;
            }
            *(float4*)(z_s + k * H + hq * 4) = v;
        }
        __syncthreads();
        #pragma unroll 8
        for (int k = 0; k < KT; ++k) {
            float ar[4];
            #pragma unroll
            for (int r = 0; r < 4; ++r) ar[r] = a_s[(ty * 4 + r) * 68 + k];
            float zv[CPT];
            #pragma unroll
            for (int u = 0; u < CPT; ++u) {
                int h = tx * CPT + u;
                if (H < HP && h >= H) h = 0;   // layer4 pad guard (compile-time)
                zv[u] = z_s[k * H + h];
            }
            #pragma unroll
            for (int r = 0; r < 4; ++r)
                #pragma unroll
                for (int u = 0; u < CPT; ++u)
                    acc[r][u] += ar[r] * zv[u];
        }
    }
    #pragma unroll
    for (int r = 0; r < 4; ++r) {
        int i = rt * 64 + ty * 4 + r;
        float di = dloc[i];
        #pragma unroll
        for (int u = 0; u < CPT; ++u) {
            int h = tx * CPT + u;
            if (H < HP && h >= H) continue;
            float self = SHARED ? di * ZG[(size_t)i * H + h] : ZG[(size_t)i * H + h];
            float v = di * (acc[r][u] + self) + bias[h];
            if (ACT) v = v >= 0.f ? v : 0.2f * v;
            xout[((size_t)bc * NN + i) * H + h] = v;
        }
    }
}

// ---------------- small GEMM: Zc[j,h] = d_j * sum_p X[j,p]*W[p,h] ----------
template<int HI, int HO>
__global__ __launch_bounds__(256) void k_smallgemm(
    const float* __restrict__ xin, const float* __restrict__ wp,
    const float* __restrict__ wn, const float* __restrict__ dinv,
    float* __restrict__ zc)
{
    constexpr int CPT = (HO >= 16) ? HO / 16 : 1;
    constexpr int XS = HI + 4;
    __shared__ float x_s[32 * XS];
    __shared__ float w_s[HI * HO];
    const int bc = blockIdx.y, jt = blockIdx.x, t = threadIdx.x;
    const int tx = t & 15, ty = t >> 4;
    const float* W = (bc & 1) ? wn : wp;
    const float* X = xin + ((size_t)bc * NN + jt * 32) * HI;
    for (int idx = t; idx < HI * HO / 4; idx += 256)
        *(float4*)(w_s + idx * 4) = *(const float4*)(W + idx * 4);
    for (int idx = t; idx < 32 * HI / 4; idx += 256) {
        int r = idx / (HI / 4), q = idx % (HI / 4);
        *(float4*)(x_s + r * XS + q * 4) = *(const float4*)(X + (size_t)r * HI + q * 4);
    }
    __syncthreads();
    float acc[2][CPT];
    #pragma unroll
    for (int r = 0; r < 2; ++r)
        #pragma unroll
        for (int u = 0; u < CPT; ++u) acc[r][u] = 0.f;
    #pragma unroll 4
    for (int p = 0; p < HI; ++p) {
        float xr[2];
        #pragma unroll
        for (int r = 0; r < 2; ++r) xr[r] = x_s[(ty * 2 + r) * XS + p];
        float wv[CPT];
        #pragma unroll
        for (int u = 0; u < CPT; ++u) {
            int h = tx * CPT + u;
            if (HO < 16 && h >= HO) h = 0;
            wv[u] = w_s[p * HO + h];
        }
        #pragma unroll
        for (int r = 0; r < 2; ++r)
            #pragma unroll
            for (int u = 0; u < CPT; ++u) acc[r][u] += xr[r] * wv[u];
    }
    const float* dloc = dinv + bc * NN;
    #pragma unroll
    for (int r = 0; r < 2; ++r) {
        int j = jt * 32 + ty * 2 + r;
        float dj = dloc[j];
        #pragma unroll
        for (int u = 0; u < CPT; ++u) {
            int h = tx * CPT + u;
            if (HO < 16 && h >= HO) continue;
            zc[((size_t)bc * NN + j) * HO + h] = dj * acc[r][u];
        }
    }
}

// ---------------- DCL head: L[bc][o*512+n] = sum_i w[o,i]*conv4flat[i*512+n]+bv[o]
__global__ __launch_bounds__(256) void k_dcl(
    const float* __restrict__ x3, const float* __restrict__ x4,
    const float* __restrict__ wc, const int* __restrict__ task,
    float* __restrict__ L)
{
    __shared__ float ps[8][32];
    __shared__ float xf[32];
    __shared__ float pr[72];
    const int bc = blockIdx.x, t = threadIdx.x;
    const float* X3 = x3 + (size_t)bc * NN * 32;
    {
        int col = t & 31, rg = t >> 5;
        float s = 0.f;
        for (int r = rg; r < NN; r += 8) s += X3[r * 32 + col];
        ps[rg][col] = s;
    }
    __syncthreads();
    if (t < 32) {
        float s = 0.f;
        #pragma unroll
        for (int g = 0; g < 8; ++g) s += ps[g][t];
        xf[t] = s * (1.0f / 512.0f);   // mean over N
    }
    __syncthreads();
    if (t < 72) {
        int tid = task[bc >> 1];
        const float* wr = wc + t * 48;
        float s = wr[32 + tid];        // one-hot picks column 32+task_id
        #pragma unroll
        for (int j = 0; j < 32; ++j) s += wr[j] * xf[j];
        pr[t] = s;
    }
    __syncthreads();
    const float* X4 = x4 + (size_t)bc * 4096;   // conv4 flat (head reshape)
    float* Lb = L + (size_t)bc * 4096;
    #pragma unroll
    for (int rep = 0; rep < 2; ++rep) {
        int n = rep * 256 + t;
        float hi[8];
        #pragma unroll
        for (int i = 0; i < 8; ++i) hi[i] = X4[i * 512 + n];
        #pragma unroll
        for (int o = 0; o < 8; ++o) {
            float s = pr[64 + o];
            #pragma unroll
            for (int i = 0; i < 8; ++i) s += pr[o * 8 + i] * hi[i];
            Lb[o * 512 + n] = s;
        }
    }
}

// ---------------- final: out[bc][n][m] = softplus(-cc_n . cc_m) ------------
// scT layout: [o][SCP] (o-major, conflict-free lane-stride-1 reads)
#define SCP 520
__global__ __launch_bounds__(256) void k_final(const float* __restrict__ L,
                                               float* __restrict__ out)
{
    __shared__ float scT[8 * SCP];
    const int bcid = blockIdx.y;
    const int b = bcid >> 1, c = bcid & 1;
    const int nt = blockIdx.x, t = threadIdx.x;
    const float* Lp = L + (size_t)(b * 2) * 4096;
    const float* Ln = Lp + 4096;
    // cc[b][c][n2][o2] = concat(lp,ln) flat reinterpretation; store transposed
    for (int rep = 0; rep < 16; ++rep) {
        int e = rep * 256 + t;          // e = n2*8 + o2
        int f = c * 4096 + e;
        int n = f >> 4, k = f & 15;     // row/col in the (512,16) concat
        float v = (k < 8) ? Lp[n * 8 + k] : Ln[n * 8 + k - 8];
        scT[(e & 7) * SCP + (e >> 3)] = v;   // 2-way bank alias = free
    }
    __syncthreads();
    const int tx = t & 63, ty = t >> 6;
    const int n0 = nt * 32 + ty * 8;
    float cn[8][8];
    #pragma unroll
    for (int o = 0; o < 8; ++o)
        #pragma unroll
        for (int i = 0; i < 8; ++i) cn[i][o] = scT[o * SCP + n0 + i];  // broadcast
    float* ob = out + (size_t)bcid * NN * NN;
    #pragma unroll 2
    for (int mg = 0; mg < 8; ++mg) {
        int m = tx + mg * 64;
        float cm[8];
        #pragma unroll
        for (int o = 0; o < 8; ++o) cm[o] = scT[o * SCP + m];  // stride-1, no conflict
        #pragma unroll
        for (int i = 0; i < 8; ++i) {
            float s = 0.f;
            #pragma unroll
            for (int o = 0; o < 8; ++o) s += cn[i][o] * cm[o];
            // softplus(-s) = max(-s,0) + log(1+exp(-|s|)) — HW exp/log
            float r = fmaxf(-s, 0.f) + __logf(1.0f + __expf(-fabsf(s)));
            ob[(size_t)(n0 + i) * NN + m] = r;
        }
    }
}

extern "C" void kernel_launch(void* const* d_in, const int* in_sizes, int n_in,
                              void* d_out, int out_size, void* d_ws, size_t ws_size,
                              hipStream_t stream)
{
    const float* adj = (const float*)d_in[0];
    const int*  task = (const int*)d_in[1];
    const float* w1p = (const float*)d_in[2];  const float* b1p = (const float*)d_in[3];
    const float* w2p = (const float*)d_in[4];  const float* b2p = (const float*)d_in[5];
    const float* w3p = (const float*)d_in[6];  const float* b3p = (const float*)d_in[7];
    const float* w4p = (const float*)d_in[8];  const float* b4p = (const float*)d_in[9];
    const float* w1n = (const float*)d_in[10]; const float* b1n = (const float*)d_in[11];
    const float* w2n = (const float*)d_in[12]; const float* b2n = (const float*)d_in[13];
    const float* w3n = (const float*)d_in[14]; const float* b3n = (const float*)d_in[15];
    const float* w4n = (const float*)d_in[16]; const float* b4n = (const float*)d_in[17];
    const float* wc  = (const float*)d_in[18];

    float* ws   = (float*)d_ws;
    float* dinv = ws;                 // 65,536 floats
    float* XA   = ws + 65536;         // 8,388,608  (X1 then reused for X2)
    float* X3   = XA + 8388608;       // 2,097,152  (conv3, kept for DCL)
    float* X4   = X3 + 2097152;       //   524,288  (conv4)
    float* L    = X4 + 524288;        //   524,288  (logits flat, (8,512) layout)
    float* ZC   = L  + 524288;        // 4,194,304  (Zc scratch, reused per layer)
    (void)in_sizes; (void)n_in; (void)out_size; (void)ws_size;

    k_rowsum<<<dim3(NBC * NN / 4), dim3(256), 0, stream>>>(adj, dinv);
    // layer 1: H=128, Zc folded from shared W1 (Zc = d_j * W1[j,h])
    k_biggemm<128,128,true ,true ><<<dim3(8,128), 256, 0, stream>>>(adj, nullptr, w1p, w1n, b1p, b1n, dinv, XA);
    k_smallgemm<128,64><<<dim3(16,128), 256, 0, stream>>>(XA, w2p, w2n, dinv, ZC);
    k_biggemm<64,64,false,true ><<<dim3(8,128), 256, 0, stream>>>(adj, ZC, nullptr, nullptr, b2p, b2n, dinv, XA);
    k_smallgemm<64,32><<<dim3(16,128), 256, 0, stream>>>(XA, w3p, w3n, dinv, ZC);
    k_biggemm<32,32,false,true ><<<dim3(8,128), 256, 0, stream>>>(adj, ZC, nullptr, nullptr, b3p, b3n, dinv, X3);
    k_smallgemm<32,8><<<dim3(16,128), 256, 0, stream>>>(X3, w4p, w4n, dinv, ZC);
    k_biggemm<8,16,false,false><<<dim3(8,128), 256, 0, stream>>>(adj, ZC, nullptr, nullptr, b4p, b4n, dinv, X4);
    k_dcl<<<dim3(128), 256, 0, stream>>>(X3, X4, wc, task, L);
    k_final<<<dim3(16,128), 256, 0, stream>>>(L, (float*)d_out);
}

// Round 3
// 572.252 us; speedup vs baseline: 1.2226x; 1.0783x over previous
//
#include <hip/hip_runtime.h>
#include <math.h>

#define NN 512
#define NBC 128   // B*2

typedef __attribute__((ext_vector_type(8))) __bf16 v8bf;
typedef __attribute__((ext_vector_type(4))) float v4f;

// round-to-nearest-even bf16 split: v = hi + lo (+O(2^-17) rel)
__device__ __forceinline__ void bsplit(float v, unsigned short& h, unsigned short& l) {
    unsigned u  = __builtin_bit_cast(unsigned, v);
    unsigned hb = (u + 0x7fffu + ((u >> 16) & 1u)) & 0xffff0000u;
    float hf    = __builtin_bit_cast(float, hb);
    h = (unsigned short)(hb >> 16);
    float lof   = v - hf;
    unsigned ul = __builtin_bit_cast(unsigned, lof);
    l = (unsigned short)((ul + 0x7fffu + ((ul >> 16) & 1u)) >> 16);
}

// ---------------- degree: dinv[bc][i] = rsqrt(1 + sum_j adj[bc][i][j]) -----
__global__ __launch_bounds__(256) void k_rowsum(const float* __restrict__ adj,
                                                float* __restrict__ dinv) {
    int wave = blockIdx.x * 4 + (threadIdx.x >> 6);
    int lane = threadIdx.x & 63;
    const float4* row = (const float4*)(adj + (size_t)wave * NN);
    float4 v0 = row[lane], v1 = row[lane + 64];
    float s = v0.x + v0.y + v0.z + v0.w + v1.x + v1.y + v1.z + v1.w;
    #pragma unroll
    for (int off = 32; off; off >>= 1) s += __shfl_down(s, off, 64);
    if (lane == 0) dinv[wave] = rsqrtf(1.0f + s);
}

// ---------------- An = D(adj+I)D  ->  bf16 hi/lo planes ---------------------
__global__ __launch_bounds__(256) void k_convert(const float* __restrict__ adj,
    const float* __restrict__ dinv, unsigned short* __restrict__ anh,
    unsigned short* __restrict__ anl)
{
    unsigned gid = blockIdx.x * 256 + threadIdx.x;
    unsigned e = gid * 4;               // element index, 4 per thread
    unsigned bc = e >> 18, rem = e & 0x3ffffu;
    unsigned i = rem >> 9, j = rem & 511u;
    float4 a = *(const float4*)(adj + (size_t)e);
    float di = dinv[bc * NN + i];
    const float4 dj = *(const float4*)(dinv + bc * NN + j);
    float v0 = di * dj.x * (a.x + ((j + 0) == i ? 1.f : 0.f));
    float v1 = di * dj.y * (a.y + ((j + 1) == i ? 1.f : 0.f));
    float v2 = di * dj.z * (a.z + ((j + 2) == i ? 1.f : 0.f));
    float v3 = di * dj.w * (a.w + ((j + 3) == i ? 1.f : 0.f));
    ushort4 hh, ll;
    bsplit(v0, hh.x, ll.x); bsplit(v1, hh.y, ll.y);
    bsplit(v2, hh.z, ll.z); bsplit(v3, hh.w, ll.w);
    *(ushort4*)(anh + e) = hh;
    *(ushort4*)(anl + e) = ll;
}

// ---------------- weight prep: dst[h][p] = split(w[p][h]) (zero-pad h>=HO) --
struct WJob  { const float* w; unsigned short* dh; unsigned short* dl; int HI; int HO; int HOP; };
struct WJobs { WJob j[8]; };
__global__ __launch_bounds__(256) void k_wprep(WJobs jobs) {
    WJob jb = jobs.j[blockIdx.y];
    int idx = blockIdx.x * 256 + threadIdx.x;
    if (idx >= jb.HOP * jb.HI) return;
    int h = idx / jb.HI, p = idx % jb.HI;
    float v = (h < jb.HO) ? jb.w[p * jb.HO + h] : 0.f;
    unsigned short hh, ll; bsplit(v, hh, ll);
    jb.dh[idx] = hh; jb.dl[idx] = ll;
}

// ---------------- MFMA layer: X = act(An @ Z + b) ---------------------------
// An: [bc][i][j] bf16 hi/lo (j contig).  Zt: [s][n=h][k=j] bf16 hi/lo (j contig).
// 3-term split: Ah@Zh + Ah@Zl + Al@Zh.  Wave = 32 rows x BN cols, 4 waves/block.
template<int BN, int OUTW, bool SHAREDZ, bool ACT, bool WBF>
__global__ __launch_bounds__(256, 2) void k_mfma(
    const unsigned short* __restrict__ anh_, const unsigned short* __restrict__ anl_,
    const unsigned short* __restrict__ zh_,  const unsigned short* __restrict__ zl_,
    const float* __restrict__ bp, const float* __restrict__ bn,
    float* __restrict__ xf, unsigned short* __restrict__ xh, unsigned short* __restrict__ xl)
{
    constexpr int C = BN / 16;
    const int bc = blockIdx.y, rb = blockIdx.x;
    const int t = threadIdx.x, w = t >> 6, lane = t & 63;
    const int m0 = lane & 15, quad = lane >> 4;
    const int rowbase = rb * 128 + w * 32;
    const int s = SHAREDZ ? (bc & 1) : bc;
    const unsigned short* pa_h = anh_ + ((size_t)bc * NN + rowbase + m0) * NN + quad * 8;
    const unsigned short* pa_l = anl_ + ((size_t)bc * NN + rowbase + m0) * NN + quad * 8;
    const unsigned short* pz_h = zh_ + ((size_t)s * BN + m0) * NN + quad * 8;
    const unsigned short* pz_l = zl_ + ((size_t)s * BN + m0) * NN + quad * 8;
    v4f acc[2][C];
    #pragma unroll
    for (int r = 0; r < 2; ++r)
        #pragma unroll
        for (int c = 0; c < C; ++c) acc[r][c] = (v4f){0.f, 0.f, 0.f, 0.f};

    for (int kb = 0; kb < 16; ++kb) {
        const int ko = kb * 32;
        v8bf zfh[C], zfl[C];
        #pragma unroll
        for (int c = 0; c < C; ++c) {
            zfh[c] = *(const v8bf*)(pz_h + (size_t)(c * 16) * NN + ko);
            zfl[c] = *(const v8bf*)(pz_l + (size_t)(c * 16) * NN + ko);
        }
        #pragma unroll
        for (int r = 0; r < 2; ++r) {
            v8bf ah = *(const v8bf*)(pa_h + (size_t)(r * 16) * NN + ko);
            v8bf al = *(const v8bf*)(pa_l + (size_t)(r * 16) * NN + ko);
            #pragma unroll
            for (int c = 0; c < C; ++c) {
                acc[r][c] = __builtin_amdgcn_mfma_f32_16x16x32_bf16(ah, zfh[c], acc[r][c], 0, 0, 0);
                acc[r][c] = __builtin_amdgcn_mfma_f32_16x16x32_bf16(ah, zfl[c], acc[r][c], 0, 0, 0);
                acc[r][c] = __builtin_amdgcn_mfma_f32_16x16x32_bf16(al, zfh[c], acc[r][c], 0, 0, 0);
            }
        }
    }
    const float* bias = (bc & 1) ? bn : bp;
    #pragma unroll
    for (int r = 0; r < 2; ++r)
        #pragma unroll
        for (int c = 0; c < C; ++c) {
            int col = c * 16 + m0;
            if (OUTW < BN && col >= OUTW) continue;
            float bv = bias[col];
            #pragma unroll
            for (int reg = 0; reg < 4; ++reg) {
                int row = rowbase + r * 16 + quad * 4 + reg;
                float v = acc[r][c][reg] + bv;
                if (ACT) v = v >= 0.f ? v : 0.2f * v;
                size_t oi = ((size_t)bc * NN + row) * OUTW + col;
                if (xf) xf[oi] = v;
                if (WBF) {
                    unsigned short hh, ll; bsplit(v, hh, ll);
                    xh[oi] = hh; xl[oi] = ll;
                }
            }
        }
}

// ---------------- MFMA Z-gemm: Zt[h][j] = sum_p W[p][h] X[j][p] -------------
// A = Wt [s][h][p] (p contig), B = X [bc][j][p] (p contig), out transposed.
template<int HI, int HOP>
__global__ __launch_bounds__(256) void k_zgemm(
    const unsigned short* __restrict__ wth, const unsigned short* __restrict__ wtl,
    const unsigned short* __restrict__ xh_, const unsigned short* __restrict__ xl_,
    unsigned short* __restrict__ zh_, unsigned short* __restrict__ zl_)
{
    constexpr int MT = HOP / 16, JW = 4 / MT, NT = 8 / JW;
    const int bc = blockIdx.y, jb = blockIdx.x;
    const int t = threadIdx.x, w = t >> 6, lane = t & 63;
    const int m0 = lane & 15, quad = lane >> 4;
    const int mt = w % MT, jseg = w / MT;
    const int n0 = jb * 128 + jseg * (128 / JW);
    const int s = bc & 1;
    const unsigned short* pw_h = wth + ((size_t)s * HOP + mt * 16 + m0) * HI + quad * 8;
    const unsigned short* pw_l = wtl + ((size_t)s * HOP + mt * 16 + m0) * HI + quad * 8;
    const unsigned short* px_h = xh_ + ((size_t)bc * NN + n0 + m0) * HI + quad * 8;
    const unsigned short* px_l = xl_ + ((size_t)bc * NN + n0 + m0) * HI + quad * 8;
    v4f acc[NT];
    #pragma unroll
    for (int c = 0; c < NT; ++c) acc[c] = (v4f){0.f, 0.f, 0.f, 0.f};
    #pragma unroll
    for (int ks = 0; ks < HI / 32; ++ks) {
        const int ko = ks * 32;
        v8bf awh = *(const v8bf*)(pw_h + ko);
        v8bf awl = *(const v8bf*)(pw_l + ko);
        #pragma unroll
        for (int c = 0; c < NT; ++c) {
            v8bf bxh = *(const v8bf*)(px_h + (size_t)(c * 16) * HI + ko);
            v8bf bxl = *(const v8bf*)(px_l + (size_t)(c * 16) * HI + ko);
            acc[c] = __builtin_amdgcn_mfma_f32_16x16x32_bf16(awh, bxh, acc[c], 0, 0, 0);
            acc[c] = __builtin_amdgcn_mfma_f32_16x16x32_bf16(awh, bxl, acc[c], 0, 0, 0);
            acc[c] = __builtin_amdgcn_mfma_f32_16x16x32_bf16(awl, bxh, acc[c], 0, 0, 0);
        }
    }
    #pragma unroll
    for (int c = 0; c < NT; ++c) {
        int j = n0 + c * 16 + m0;
        #pragma unroll
        for (int reg = 0; reg < 4; ++reg) {
            int h = mt * 16 + quad * 4 + reg;
            unsigned short hh, ll; bsplit(acc[c][reg], hh, ll);
            size_t oi = ((size_t)bc * HOP + h) * NN + j;
            zh_[oi] = hh; zl_[oi] = ll;
        }
    }
}

// ================= FALLBACK (R2 proven path, fp32 vector) ===================
template<int H, int HP, bool SHARED, bool ACT>
__global__ __launch_bounds__(256) void k_biggemm(
    const float* __restrict__ adj, const float* __restrict__ zcg,
    const float* __restrict__ wp, const float* __restrict__ wn,
    const float* __restrict__ bp, const float* __restrict__ bn,
    const float* __restrict__ dinv, float* __restrict__ xout)
{
    constexpr int CPT = HP / 16;
    constexpr int KT = 64;
    __shared__ float a_s[64 * 68];
    __shared__ float z_s[KT * H];
    const int bc = blockIdx.y;
    const int rt = blockIdx.x;
    const int t  = threadIdx.x;
    const int tx = t & 15, ty = t >> 4;
    const float* A    = adj + (size_t)bc * NN * NN + (size_t)rt * 64 * NN;
    const float* dloc = dinv + bc * NN;
    const float* ZG   = SHARED ? ((bc & 1) ? wn : wp) : (zcg + (size_t)bc * NN * H);
    const float* bias = (bc & 1) ? bn : bp;
    float acc[4][CPT];
    #pragma unroll
    for (int r = 0; r < 4; ++r)
        #pragma unroll
        for (int u = 0; u < CPT; ++u) acc[r][u] = 0.f;
    for (int kb = 0; kb < NN; kb += KT) {
        __syncthreads();
        #pragma unroll
        for (int l = 0; l < 4; ++l) {
            int idx = t + l * 256;
            int r = idx >> 4, q = idx & 15;
            float4 v = *(const float4*)(A + (size_t)r * NN + kb + q * 4);
            *(float4*)(a_s + r * 68 + q * 4) = v;
        }
        constexpr int NZ4 = KT * H / 4;
        for (int idx = t; idx < NZ4; idx += 256) {
            int k = idx / (H / 4), hq = idx % (H / 4);
            float4 v = *(const float4*)(ZG + (size_t)(kb + k) * H + hq * 4);
            if (SHARED) {
                float dk = dloc[kb + k];
                v.x *= dk; v.y *= dk; v.z *= dk; v.w *= dk;
            }
            *(float4*)(z_s + k * H + hq * 4) = v;
        }
        __syncthreads();
        #pragma unroll 8
        for (int k = 0; k < KT; ++k) {
            float ar[4];
            #pragma unroll
            for (int r = 0; r < 4; ++r) ar[r] = a_s[(ty * 4 + r) * 68 + k];
            float zv[CPT];
            #pragma unroll
            for (int u = 0; u < CPT; ++u) {
                int h = tx * CPT + u;
                if (H < HP && h >= H) h = 0;
                zv[u] = z_s[k * H + h];
            }
            #pragma unroll
            for (int r = 0; r < 4; ++r)
                #pragma unroll
                for (int u = 0; u < CPT; ++u)
                    acc[r][u] += ar[r] * zv[u];
        }
    }
    #pragma unroll
    for (int r = 0; r < 4; ++r) {
        int i = rt * 64 + ty * 4 + r;
        float di = dloc[i];
        #pragma unroll
        for (int u = 0; u < CPT; ++u) {
            int h = tx * CPT + u;
            if (H < HP && h >= H) continue;
            float self = SHARED ? di * ZG[(size_t)i * H + h] : ZG[(size_t)i * H + h];
            float v = di * (acc[r][u] + self) + bias[h];
            if (ACT) v = v >= 0.f ? v : 0.2f * v;
            xout[((size_t)bc * NN + i) * H + h] = v;
        }
    }
}

template<int HI, int HO>
__global__ __launch_bounds__(256) void k_smallgemm(
    const float* __restrict__ xin, const float* __restrict__ wp,
    const float* __restrict__ wn, const float* __restrict__ dinv,
    float* __restrict__ zc)
{
    constexpr int CPT = (HO >= 16) ? HO / 16 : 1;
    constexpr int XS = HI + 4;
    __shared__ float x_s[32 * XS];
    __shared__ float w_s[HI * HO];
    const int bc = blockIdx.y, jt = blockIdx.x, t = threadIdx.x;
    const int tx = t & 15, ty = t >> 4;
    const float* W = (bc & 1) ? wn : wp;
    const float* X = xin + ((size_t)bc * NN + jt * 32) * HI;
    for (int idx = t; idx < HI * HO / 4; idx += 256)
        *(float4*)(w_s + idx * 4) = *(const float4*)(W + idx * 4);
    for (int idx = t; idx < 32 * HI / 4; idx += 256) {
        int r = idx / (HI / 4), q = idx % (HI / 4);
        *(float4*)(x_s + r * XS + q * 4) = *(const float4*)(X + (size_t)r * HI + q * 4);
    }
    __syncthreads();
    float acc[2][CPT];
    #pragma unroll
    for (int r = 0; r < 2; ++r)
        #pragma unroll
        for (int u = 0; u < CPT; ++u) acc[r][u] = 0.f;
    #pragma unroll 4
    for (int p = 0; p < HI; ++p) {
        float xr[2];
        #pragma unroll
        for (int r = 0; r < 2; ++r) xr[r] = x_s[(ty * 2 + r) * XS + p];
        float wv[CPT];
        #pragma unroll
        for (int u = 0; u < CPT; ++u) {
            int h = tx * CPT + u;
            if (HO < 16 && h >= HO) h = 0;
            wv[u] = w_s[p * HO + h];
        }
        #pragma unroll
        for (int r = 0; r < 2; ++r)
            #pragma unroll
            for (int u = 0; u < CPT; ++u) acc[r][u] += xr[r] * wv[u];
    }
    const float* dloc = dinv + bc * NN;
    #pragma unroll
    for (int r = 0; r < 2; ++r) {
        int j = jt * 32 + ty * 2 + r;
        float dj = dloc[j];
        #pragma unroll
        for (int u = 0; u < CPT; ++u) {
            int h = tx * CPT + u;
            if (HO < 16 && h >= HO) continue;
            zc[((size_t)bc * NN + j) * HO + h] = dj * acc[r][u];
        }
    }
}

// ---------------- DCL head (shared by both paths) ---------------------------
__global__ __launch_bounds__(256) void k_dcl(
    const float* __restrict__ x3, const float* __restrict__ x4,
    const float* __restrict__ wc, const int* __restrict__ task,
    float* __restrict__ L)
{
    __shared__ float ps[8][32];
    __shared__ float xf[32];
    __shared__ float pr[72];
    const int bc = blockIdx.x, t = threadIdx.x;
    const float* X3 = x3 + (size_t)bc * NN * 32;
    {
        int col = t & 31, rg = t >> 5;
        float s = 0.f;
        for (int r = rg; r < NN; r += 8) s += X3[r * 32 + col];
        ps[rg][col] = s;
    }
    __syncthreads();
    if (t < 32) {
        float s = 0.f;
        #pragma unroll
        for (int g = 0; g < 8; ++g) s += ps[g][t];
        xf[t] = s * (1.0f / 512.0f);
    }
    __syncthreads();
    if (t < 72) {
        int tid = task[bc >> 1];
        const float* wr = wc + t * 48;
        float s = wr[32 + tid];
        #pragma unroll
        for (int j = 0; j < 32; ++j) s += wr[j] * xf[j];
        pr[t] = s;
    }
    __syncthreads();
    const float* X4 = x4 + (size_t)bc * 4096;
    float* Lb = L + (size_t)bc * 4096;
    #pragma unroll
    for (int rep = 0; rep < 2; ++rep) {
        int n = rep * 256 + t;
        float hi[8];
        #pragma unroll
        for (int i = 0; i < 8; ++i) hi[i] = X4[i * 512 + n];
        #pragma unroll
        for (int o = 0; o < 8; ++o) {
            float s = pr[64 + o];
            #pragma unroll
            for (int i = 0; i < 8; ++i) s += pr[o * 8 + i] * hi[i];
            Lb[o * 512 + n] = s;
        }
    }
}

// ---------------- final: out[bc][n][m] = softplus(-cc_n . cc_m) -------------
#define SCP 520
__global__ __launch_bounds__(256) void k_final(const float* __restrict__ L,
                                               float* __restrict__ out)
{
    __shared__ float scT[8 * SCP];
    const int bcid = blockIdx.y;
    const int b = bcid >> 1, c = bcid & 1;
    const int nt = blockIdx.x, t = threadIdx.x;
    const float* Lp = L + (size_t)(b * 2) * 4096;
    const float* Ln = Lp + 4096;
    for (int rep = 0; rep < 16; ++rep) {
        int e = rep * 256 + t;
        int f = c * 4096 + e;
        int n = f >> 4, k = f & 15;
        float v = (k < 8) ? Lp[n * 8 + k] : Ln[n * 8 + k - 8];
        scT[(e & 7) * SCP + (e >> 3)] = v;
    }
    __syncthreads();
    const int tx = t & 63, ty = t >> 6;
    const int n0 = nt * 32 + ty * 8;
    float cn[8][8];
    #pragma unroll
    for (int o = 0; o < 8; ++o)
        #pragma unroll
        for (int i = 0; i < 8; ++i) cn[i][o] = scT[o * SCP + n0 + i];
    float* ob = out + (size_t)bcid * NN * NN;
    #pragma unroll 2
    for (int mg = 0; mg < 8; ++mg) {
        int m = tx + mg * 64;
        float cm[8];
        #pragma unroll
        for (int o = 0; o < 8; ++o) cm[o] = scT[o * SCP + m];
        #pragma unroll
        for (int i = 0; i < 8; ++i) {
            float s = 0.f;
            #pragma unroll
            for (int o = 0; o < 8; ++o) s += cn[i][o] * cm[o];
            float r = fmaxf(-s, 0.f) + __logf(1.0f + __expf(-fabsf(s)));
            ob[(size_t)(n0 + i) * NN + m] = r;
        }
    }
}

extern "C" void kernel_launch(void* const* d_in, const int* in_sizes, int n_in,
                              void* d_out, int out_size, void* d_ws, size_t ws_size,
                              hipStream_t stream)
{
    const float* adj = (const float*)d_in[0];
    const int*  task = (const int*)d_in[1];
    const float* w1p = (const float*)d_in[2];  const float* b1p = (const float*)d_in[3];
    const float* w2p = (const float*)d_in[4];  const float* b2p = (const float*)d_in[5];
    const float* w3p = (const float*)d_in[6];  const float* b3p = (const float*)d_in[7];
    const float* w4p = (const float*)d_in[8];  const float* b4p = (const float*)d_in[9];
    const float* w1n = (const float*)d_in[10]; const float* b1n = (const float*)d_in[11];
    const float* w2n = (const float*)d_in[12]; const float* b2n = (const float*)d_in[13];
    const float* w3n = (const float*)d_in[14]; const float* b3n = (const float*)d_in[15];
    const float* w4n = (const float*)d_in[16]; const float* b4n = (const float*)d_in[17];
    const float* wc  = (const float*)d_in[18];
    (void)in_sizes; (void)n_in; (void)out_size;

    const size_t NEED = 198004736ull;
    if (ws_size >= NEED) {
        char* base = (char*)d_ws;
        float*          dinv = (float*)(base + 0);
        unsigned short* anh  = (unsigned short*)(base + 262144);
        unsigned short* anl  = (unsigned short*)(base + 67371008);
        unsigned short* zt1h = (unsigned short*)(base + 134479872);
        unsigned short* zt1l = (unsigned short*)(base + 134742016);
        unsigned short* wt2h = (unsigned short*)(base + 135004160);
        unsigned short* wt2l = (unsigned short*)(base + 135036928);
        unsigned short* wt3h = (unsigned short*)(base + 135069696);
        unsigned short* wt3l = (unsigned short*)(base + 135077888);
        unsigned short* wt4h = (unsigned short*)(base + 135086080);
        unsigned short* wt4l = (unsigned short*)(base + 135088128);
        unsigned short* x1h  = (unsigned short*)(base + 135090176);
        unsigned short* x1l  = (unsigned short*)(base + 151867392);
        unsigned short* zt2h = (unsigned short*)(base + 168644608);
        unsigned short* zt2l = (unsigned short*)(base + 177033216);
        float*          x3f  = (float*)(base + 185421824);
        float*          x4f  = (float*)(base + 193810432);
        float*          L    = (float*)(base + 195907584);
        // aliases (lifetimes disjoint across kernel boundaries)
        unsigned short* x2h = x1h,  *x2l = x1l;
        unsigned short* x3h = x1h,  *x3l = x1l;
        unsigned short* zt3h = zt2h, *zt3l = zt2l;
        unsigned short* zt4h = zt2h, *zt4l = zt2l;

        k_rowsum<<<dim3(NBC * NN / 4), 256, 0, stream>>>(adj, dinv);
        k_convert<<<dim3(32768), 256, 0, stream>>>(adj, dinv, anh, anl);
        WJobs jobs;
        jobs.j[0] = {w1p, zt1h,          zt1l,          512, 128, 128};
        jobs.j[1] = {w1n, zt1h + 65536,  zt1l + 65536,  512, 128, 128};
        jobs.j[2] = {w2p, wt2h,          wt2l,          128,  64,  64};
        jobs.j[3] = {w2n, wt2h + 8192,   wt2l + 8192,   128,  64,  64};
        jobs.j[4] = {w3p, wt3h,          wt3l,           64,  32,  32};
        jobs.j[5] = {w3n, wt3h + 2048,   wt3l + 2048,    64,  32,  32};
        jobs.j[6] = {w4p, wt4h,          wt4l,           32,   8,  16};
        jobs.j[7] = {w4n, wt4h + 512,    wt4l + 512,     32,   8,  16};
        k_wprep<<<dim3(256, 8), 256, 0, stream>>>(jobs);

        k_mfma<128, 128, true,  true,  true ><<<dim3(4, NBC), 256, 0, stream>>>(
            anh, anl, zt1h, zt1l, b1p, b1n, nullptr, x1h, x1l);
        k_zgemm<128, 64><<<dim3(4, NBC), 256, 0, stream>>>(wt2h, wt2l, x1h, x1l, zt2h, zt2l);
        k_mfma<64, 64, false, true,  true ><<<dim3(4, NBC), 256, 0, stream>>>(
            anh, anl, zt2h, zt2l, b2p, b2n, nullptr, x2h, x2l);
        k_zgemm<64, 32><<<dim3(4, NBC), 256, 0, stream>>>(wt3h, wt3l, x2h, x2l, zt3h, zt3l);
        k_mfma<32, 32, false, true,  true ><<<dim3(4, NBC), 256, 0, stream>>>(
            anh, anl, zt3h, zt3l, b3p, b3n, x3f, x3h, x3l);
        k_zgemm<32, 16><<<dim3(4, NBC), 256, 0, stream>>>(wt4h, wt4l, x3h, x3l, zt4h, zt4l);
        k_mfma<16, 8, false, false, false><<<dim3(4, NBC), 256, 0, stream>>>(
            anh, anl, zt4h, zt4l, b4p, b4n, x4f, nullptr, nullptr);
        k_dcl<<<dim3(NBC), 256, 0, stream>>>(x3f, x4f, wc, task, L);
        k_final<<<dim3(16, NBC), 256, 0, stream>>>(L, (float*)d_out);
    } else {
        // -------- fallback: proven R2 fp32 path (needs ~63 MB) --------
        float* ws   = (float*)d_ws;
        float* dinv = ws;
        float* XA   = ws + 65536;
        float* X3   = XA + 8388608;
        float* X4   = X3 + 2097152;
        float* L    = X4 + 524288;
        float* ZC   = L  + 524288;
        k_rowsum<<<dim3(NBC * NN / 4), 256, 0, stream>>>(adj, dinv);
        k_biggemm<128,128,true ,true ><<<dim3(8,128), 256, 0, stream>>>(adj, nullptr, w1p, w1n, b1p, b1n, dinv, XA);
        k_smallgemm<128,64><<<dim3(16,128), 256, 0, stream>>>(XA, w2p, w2n, dinv, ZC);
        k_biggemm<64,64,false,true ><<<dim3(8,128), 256, 0, stream>>>(adj, ZC, nullptr, nullptr, b2p, b2n, dinv, XA);
        k_smallgemm<64,32><<<dim3(16,128), 256, 0, stream>>>(XA, w3p, w3n, dinv, ZC);
        k_biggemm<32,32,false,true ><<<dim3(8,128), 256, 0, stream>>>(adj, ZC, nullptr, nullptr, b3p, b3n, dinv, X3);
        k_smallgemm<32,8><<<dim3(16,128), 256, 0, stream>>>(X3, w4p, w4n, dinv, ZC);
        k_biggemm<8,16,false,false><<<dim3(8,128), 256, 0, stream>>>(adj, ZC, nullptr, nullptr, b4p, b4n, dinv, X4);
        k_dcl<<<dim3(128), 256, 0, stream>>>(X3, X4, wc, task, L);
        k_final<<<dim3(16,128), 256, 0, stream>>>(L, (float*)d_out);
    }
}